// Round 6
// baseline (165.057 us; speedup 1.0000x reference)
//
#include <hip/hip_runtime.h>
#include <hip/hip_bf16.h>

typedef __attribute__((ext_vector_type(8))) short short8;
typedef __attribute__((ext_vector_type(4))) short short4v;
typedef __attribute__((ext_vector_type(4))) float f32x4;

#define NB      8
#define NSEQ    4096
#define NDIM    512
#define NHEADS  8
#define NDH     32
#define NINNER  256          // NHEADS*NDH
#define NCHUNK  32
#define TCH     128          // NSEQ / NCHUNK == BM
#define MROWS   (NB*NSEQ)    // 32768

__device__ __forceinline__ short f2bf(float x) {
  union { float f; unsigned u; } v; v.f = x;
  unsigned r = (v.u + 0x7FFFu + ((v.u >> 16) & 1u)) >> 16;   // RNE
  return (short)(unsigned short)r;
}
__device__ __forceinline__ float bf2f(short s) {
  union { unsigned u; float f; } v; v.u = ((unsigned)(unsigned short)s) << 16;
  return v.f;
}
__device__ __forceinline__ float sigmoidf_(float x) {
  return 1.0f / (1.0f + expf(-x));
}

// ---------------------------------------------------------------------------
// prep: both W transposes+converts in ONE launch.
//   blocks 0..127:   W_in  (512x256) -> WinT  [256][512] bf16
//   blocks 128..255: W_out (256x512) -> WoutT [512][256] bf16
// ---------------------------------------------------------------------------
__global__ __launch_bounds__(256) void prep_kernel(
    const float* __restrict__ W_in, const float* __restrict__ W_out,
    short* __restrict__ WinT, short* __restrict__ WoutT)
{
  __shared__ short T[32][33];
  const float* src; short* dst; int K, N, tile;
  if (blockIdx.x < 128) { src = W_in;  dst = WinT;  K = NDIM;   N = NINNER; tile = blockIdx.x; }
  else                  { src = W_out; dst = WoutT; K = NINNER; N = NDIM;   tile = blockIdx.x - 128; }
  const int tiles_n = N >> 5;
  const int ki = tile / tiles_n, ni = tile % tiles_n;
  const int tx = threadIdx.x & 31, ty0 = threadIdx.x >> 5;
  #pragma unroll
  for (int r = 0; r < 4; ++r) {
    int ty = ty0 + r * 8;
    T[ty][tx] = f2bf(src[(size_t)(ki * 32 + ty) * N + ni * 32 + tx]);
  }
  __syncthreads();
  #pragma unroll
  for (int r = 0; r < 4; ++r) {
    int ty = ty0 + r * 8;
    dst[(size_t)(ni * 32 + ty) * K + ki * 32 + tx] = T[tx][ty];
  }
}

// ---------------------------------------------------------------------------
// Kernel 1: GEMM1 (xp = x @ W_in + b_in) fused with local EMA-sum scan.
//   BM=128(=chunk) BN=128 BK=64. 4 waves (2x2), 16x16x32 bf16 MFMA.
//   Epilogue: tile -> LDS bf16 X[128][140]; per-column scan
//     u[tau] = a*xp[tau] - a^2*E[tau-1];  E[tau] = cc*E[tau-1] + xp[tau]
//   writes u (bf16) and E[127] -> Lfin.
//   Static LDS union { As[128][72]+Bs[128][72] | X[128][140] } = 36864 B
//   -> 4 blocks/CU (16 waves/CU).
// ---------------------------------------------------------------------------
__global__ __launch_bounds__(256, 4) void gemm1_scan_kernel(
    const float* __restrict__ x, const short* __restrict__ WinT,
    const float* __restrict__ b_in, const float* __restrict__ alpha_param,
    short* __restrict__ u, float* __restrict__ Lfin)
{
  constexpr int K = NDIM, BK = 64;
  __shared__ __align__(16) char smem[36864];
  short (*As)[72]  = reinterpret_cast<short(*)[72]>(smem);
  short (*Bs)[72]  = reinterpret_cast<short(*)[72]>(smem + 18432);
  short (*X)[140]  = reinterpret_cast<short(*)[140]>(smem);   // 35840 B

  const int tid = threadIdx.x;
  const int nwg = gridDim.x;                       // 512, %8==0
  const int tile = (blockIdx.x & 7) * (nwg >> 3) + (blockIdx.x >> 3);
  const int bm = tile >> 1;                        // tiles_n = 2
  const int bn = tile & 1;
  const int wave = tid >> 6, lane = tid & 63;
  const int wm = wave >> 1, wn = wave & 1;
  const int lr = lane & 15, lg = lane >> 4;

  f32x4 acc[4][4] = {};

  for (int kt = 0; kt < K; kt += BK) {
    // stage A: x fp32 -> bf16
    #pragma unroll
    for (int i = 0; i < 4; ++i) {
      int idx = tid + i * 256;                     // 0..1023
      int row = idx >> 3, k8 = idx & 7;
      const float4* src = reinterpret_cast<const float4*>(
          &x[(size_t)(bm * 128 + row) * K + kt + k8 * 8]);
      float4 v0 = src[0], v1 = src[1];
      short8 s;
      s[0] = f2bf(v0.x); s[1] = f2bf(v0.y); s[2] = f2bf(v0.z); s[3] = f2bf(v0.w);
      s[4] = f2bf(v1.x); s[5] = f2bf(v1.y); s[6] = f2bf(v1.z); s[7] = f2bf(v1.w);
      *reinterpret_cast<short8*>(&As[row][k8 * 8]) = s;
    }
    // stage B: pre-converted bf16 [n][k], straight vector copy
    #pragma unroll
    for (int i = 0; i < 4; ++i) {
      int idx = tid + i * 256;
      int n = idx >> 3, k8 = idx & 7;
      *reinterpret_cast<short8*>(&Bs[n][k8 * 8]) =
          *reinterpret_cast<const short8*>(&WinT[(size_t)(bn * 128 + n) * K + kt + k8 * 8]);
    }
    __syncthreads();
    #pragma unroll
    for (int ks = 0; ks < 2; ++ks) {
      short8 af[4], bf[4];
      #pragma unroll
      for (int m = 0; m < 4; ++m)
        af[m] = *reinterpret_cast<const short8*>(&As[wm * 64 + m * 16 + lr][ks * 32 + lg * 8]);
      #pragma unroll
      for (int n = 0; n < 4; ++n)
        bf[n] = *reinterpret_cast<const short8*>(&Bs[wn * 64 + n * 16 + lr][ks * 32 + lg * 8]);
      #pragma unroll
      for (int m = 0; m < 4; ++m)
        #pragma unroll
        for (int n = 0; n < 4; ++n)
          acc[m][n] = __builtin_amdgcn_mfma_f32_16x16x32_bf16(af[m], bf[n], acc[m][n], 0, 0, 0);
    }
    __syncthreads();
  }

  // epilogue: acc + bias -> LDS X (bf16)
  #pragma unroll
  for (int m = 0; m < 4; ++m) {
    int r0 = wm * 64 + m * 16 + lg * 4;
    #pragma unroll
    for (int n = 0; n < 4; ++n) {
      int cl = wn * 64 + n * 16 + lr;
      float bv = b_in[bn * 128 + cl];
      #pragma unroll
      for (int j = 0; j < 4; ++j) X[r0 + j][cl] = f2bf(acc[m][n][j] + bv);
    }
  }
  __syncthreads();

  // per-column local scan (threads 0..127), batch-8
  if (tid < 128) {
    int col = bn * 128 + tid;
    float a = sigmoidf_(alpha_param[col >> 5]);
    float cc = 1.0f - a, a2 = a * a;
    float E = 0.0f;
    for (int t0 = 0; t0 < 128; t0 += 8) {
      float xv[8];
      #pragma unroll
      for (int i = 0; i < 8; ++i) xv[i] = bf2f(X[t0 + i][tid]);
      short uu[8];
      #pragma unroll
      for (int i = 0; i < 8; ++i) {
        uu[i] = f2bf(fmaf(-a2, E, a * xv[i]));
        E = fmaf(cc, E, xv[i]);
      }
      #pragma unroll
      for (int i = 0; i < 8; ++i) X[t0 + i][tid] = uu[i];
    }
    Lfin[bm * 256 + col] = E;
  }
  __syncthreads();

  // coalesced u write (bf16), short4 units
  #pragma unroll
  for (int i = 0; i < 16; ++i) {
    int e = tid + i * 256;                         // 0..4095
    int r = e >> 5, c4 = e & 31;
    short4v s = *reinterpret_cast<const short4v*>(&X[r][c4 * 4]);
    *reinterpret_cast<short4v*>(&u[(size_t)(bm * 128 + r) * NINNER + bn * 128 + c4 * 4]) = s;
  }
}

// ---------------------------------------------------------------------------
// Kernel 2: GEMM2 (out = o @ W_out + b_out), carry computed IN-BLOCK from Lfin:
//   c = bm&31, b = bm>>5;  C = sum_{j<c} cT^{c-1-j} Lfin[b,j,col]
//   Gs[col] = -a^2*C + (cc-a)*init[col]*cc^{128c};  Ps[h][tau] = cc_h^tau (bf16)
//   A-staging injects: o[row,k] = u[row,k] + Ps[h(k)][row]*Gs[k]
//   Static LDS = 36864 + 1024 + 2048 = 39936 B -> 4 blocks/CU.
// ---------------------------------------------------------------------------
__global__ __launch_bounds__(256, 4) void gemm2_kernel(
    const short* __restrict__ u, const short* __restrict__ WoutT,
    const float* __restrict__ Lfin, const float* __restrict__ init_state,
    const float* __restrict__ alpha_param, const float* __restrict__ b_out,
    float* __restrict__ out)
{
  constexpr int K = NINNER, BK = 64, NOUT = NDIM;
  __shared__ short As[128][72];
  __shared__ short Bs[128][72];
  __shared__ float Gs[256];
  __shared__ short Ps[1024];

  const int tid = threadIdx.x;
  const int nwg = gridDim.x;                       // 1024, %8==0
  const int tile = (blockIdx.x & 7) * (nwg >> 3) + (blockIdx.x >> 3);
  const int bm = tile >> 2;                        // tiles_n = 4
  const int bn = tile & 3;
  const int wave = tid >> 6, lane = tid & 63;
  const int wm = wave >> 1, wn = wave & 1;
  const int lr = lane & 15, lg = lane >> 4;

  // ---- in-block carry + tables ----
  {
    const int col = tid;                           // 0..255
    float a    = sigmoidf_(alpha_param[col >> 5]);
    float cc   = 1.0f - a;
    float l2cc = log2f(cc);
    const int c = bm & 31, b = bm >> 5;
    float cT = exp2f(128.0f * l2cc);
    float C = 0.0f;
    for (int j = 0; j < c; ++j)
      C = fmaf(cT, C, Lfin[(size_t)(b * NCHUNK + j) * 256 + col]);
    float ccpc = exp2f(128.0f * (float)c * l2cc);
    Gs[col] = fmaf(-a * a, C, (cc - a) * init_state[col] * ccpc);
    #pragma unroll
    for (int i = 0; i < 4; ++i) {
      int idx = tid + i * 256;
      int h = idx >> 7, t = idx & 127;
      float ah = sigmoidf_(alpha_param[h]);
      Ps[idx] = f2bf(exp2f((float)t * log2f(1.0f - ah)));
    }
  }
  __syncthreads();

  f32x4 acc[4][4] = {};

  for (int kt = 0; kt < K; kt += BK) {
    // stage A: u bf16 + carry injection -> bf16
    #pragma unroll
    for (int i = 0; i < 4; ++i) {
      int idx = tid + i * 256;
      int row = idx >> 3, k8 = idx & 7;
      int kc = kt + k8 * 8;
      short8 uv = *reinterpret_cast<const short8*>(&u[(size_t)(bm * 128 + row) * K + kc]);
      float ccp = bf2f(Ps[(kc >> 5) * 128 + row]);
      short8 s;
      #pragma unroll
      for (int j = 0; j < 8; ++j)
        s[j] = f2bf(fmaf(ccp, Gs[kc + j], bf2f(uv[j])));
      *reinterpret_cast<short8*>(&As[row][k8 * 8]) = s;
    }
    // stage B
    #pragma unroll
    for (int i = 0; i < 4; ++i) {
      int idx = tid + i * 256;
      int n = idx >> 3, k8 = idx & 7;
      *reinterpret_cast<short8*>(&Bs[n][k8 * 8]) =
          *reinterpret_cast<const short8*>(&WoutT[(size_t)(bn * 128 + n) * K + kt + k8 * 8]);
    }
    __syncthreads();
    #pragma unroll
    for (int ks = 0; ks < 2; ++ks) {
      short8 af[4], bf[4];
      #pragma unroll
      for (int m = 0; m < 4; ++m)
        af[m] = *reinterpret_cast<const short8*>(&As[wm * 64 + m * 16 + lr][ks * 32 + lg * 8]);
      #pragma unroll
      for (int n = 0; n < 4; ++n)
        bf[n] = *reinterpret_cast<const short8*>(&Bs[wn * 64 + n * 16 + lr][ks * 32 + lg * 8]);
      #pragma unroll
      for (int m = 0; m < 4; ++m)
        #pragma unroll
        for (int n = 0; n < 4; ++n)
          acc[m][n] = __builtin_amdgcn_mfma_f32_16x16x32_bf16(af[m], bf[n], acc[m][n], 0, 0, 0);
    }
    __syncthreads();
  }

  #pragma unroll
  for (int m = 0; m < 4; ++m) {
    int row0 = bm * 128 + wm * 64 + m * 16 + lg * 4;
    #pragma unroll
    for (int n = 0; n < 4; ++n) {
      int col = bn * 128 + wn * 64 + n * 16 + lr;
      float bv = b_out[col];
      #pragma unroll
      for (int j = 0; j < 4; ++j)
        out[(size_t)(row0 + j) * NOUT + col] = acc[m][n][j] + bv;
    }
  }
}

// ---------------------------------------------------------------------------
extern "C" void kernel_launch(void* const* d_in, const int* in_sizes, int n_in,
                              void* d_out, int out_size, void* d_ws, size_t ws_size,
                              hipStream_t stream)
{
  const float* x           = (const float*)d_in[0];
  const float* W_in        = (const float*)d_in[1];
  const float* b_in        = (const float*)d_in[2];
  const float* W_out       = (const float*)d_in[3];
  const float* b_out       = (const float*)d_in[4];
  const float* init_state  = (const float*)d_in[5];
  const float* alpha_param = (const float*)d_in[6];
  float* out = (float*)d_out;

  char* ws = (char*)d_ws;
  short* u     = (short*)ws;                              // 16777216 B (bf16)
  float* Lfin  = (float*)(ws + 16777216);                 // 262144 B
  short* WinT  = (short*)(ws + 16777216 + 262144);        // 262144 B
  short* WoutT = (short*)(ws + 16777216 + 2 * 262144);    // 262144 B

  // one prep launch: both weight transposes/converts
  prep_kernel<<<256, 256, 0, stream>>>(W_in, W_out, WinT, WoutT);

  // GEMM1 + local scan  (grid 512 = 256 bm x 2 bn)
  gemm1_scan_kernel<<<(MROWS / 128) * (NINNER / 128), 256, 0, stream>>>(
      x, WinT, b_in, alpha_param, u, Lfin);

  // GEMM2 + in-block carry + injection  (grid 1024 = 256 bm x 4 bn)
  gemm2_kernel<<<(MROWS / 128) * (NDIM / 128), 256, 0, stream>>>(
      u, WoutT, Lfin, init_state, alpha_param, b_out, out);
}